// Round 21
// baseline (52.303 us; speedup 1.0000x reference)
//
#include <hip/hip_runtime.h>
#include <math.h>

#define BATCH 512
#define HH 224
#define WW 224
#define NPIX (HH * WW)
#define NL 3
#define EPSV 1e-5f
#define GROUPS 8             // strips per image (one per WAVE), 28 rows each

typedef float v2f __attribute__((ext_vector_type(2)));
#define PK2(s) ((v2f){(s), (s)})

// ---------------- Kernel 1: conv3x3(1->4) + relu + partial sums ----------------
// R18 packed pipeline with ZERO DS ops in the hot loop (final experiment).
// R20 post-mortem: conv is memory-insensitive (cold==warm profiled) and
// TLP/packing-insensitive -> residual ~50% stall suspected = per-row
// shfl (ds_bpermute->lgkm->mov) chains. Replace with 2 overlapping float4
// loads per row: vL@(c-1) serves pixels 0,1; vR@(c+1) serves pixels 2,3.
// Row window = uniform W[8] built by 8 cndmasks (edge remaps for lane0/55
// folded in; masks computed once). Unaligned dwordx4 is 4B-legal; extra
// memory transactions are free (not memory bound). Kill criterion: >=40us
// -> DS theory falsified, R18 final.
// Lessons: R2 zero clamped lanes; R5 no min-waves; R6/R9 fences; R13 per-wave
// partials; R18 channel-packed v2f math (18 pk_fma/px).
__global__ __launch_bounds__(256) void conv_pool_k(
    const float* __restrict__ x, const float* __restrict__ cw,
    float* __restrict__ part)
{
  const int tid = threadIdx.x;
  const int wv = tid >> 6;
  const int lane = tid & 63;
  const int W = blockIdx.x * 4 + wv;   // global wave id
  const int b = W >> 3;                // image
  const int s = W & 7;                 // strip
  const int base = s * 28;             // first output row of strip
  const int le = lane < 56 ? lane : 55;
  const int c = le * 4;
  const int cLo = (le == 0) ? 0 : c - 1;      // left quad col (clamped)
  const int cRo = (le == 55) ? 220 : c + 1;   // right quad col (clamped)
  const float* __restrict__ img = x + (size_t)b * NPIX;

  // packed weights: ch(0,1) and ch(2,3) pairs (wave-uniform)
  v2f K01[9], K23[9];
#pragma unroll
  for (int k = 0; k < 9; ++k) {
    K01[k] = (v2f){cw[k],      cw[9 + k]};
    K23[k] = (v2f){cw[18 + k], cw[27 + k]};
  }

  const bool l0 = (lane == 0), l55 = (lane == 55);

  // row-clamped dual load
  auto ldL = [&](int ar) -> float4 {
    int rc = ar < 0 ? 0 : (ar > HH - 1 ? HH - 1 : ar);
    return *reinterpret_cast<const float4*>(img + (size_t)rc * WW + cLo);
  };
  auto ldR = [&](int ar) -> float4 {
    int rc = ar < 0 ? 0 : (ar > HH - 1 ? HH - 1 : ar);
    return *reinterpret_cast<const float4*>(img + (size_t)rc * WW + cRo);
  };
  // build uniform 8-float window; p0:(W0,W1,W2) p1:(W1,W2,W3)
  //                               p2:(W4,W5,W6) p3:(W5,W6,W7)
  auto mkW = [&](const float4& vL, const float4& vR, float (&Wr)[8]) {
    Wr[0] = l0 ? 0.f : vL.x;
    Wr[1] = l0 ? vL.x : vL.y;
    Wr[2] = l0 ? vL.y : vL.z;
    Wr[3] = l0 ? vL.z : vL.w;
    Wr[4] = l55 ? vR.y : vR.x;
    Wr[5] = l55 ? vR.z : vR.y;
    Wr[6] = l55 ? vR.w : vR.z;
    Wr[7] = l55 ? 0.f : vR.w;
  };

  // prologue: rows base-1 .. base+4 -> WR[0..5]
  float WR[6][8];
  {
#pragma unroll
    for (int k = 0; k < 6; ++k) {
      float4 vL = ldL(base - 1 + k);
      float4 vR = ldR(base - 1 + k);
      mkW(vL, vR, WR[k]);
    }
    if (s == 0) {                      // row -1 is zero
#pragma unroll
      for (int q = 0; q < 8; ++q) WR[0][q] = 0.f;
    }
  }

  v2f acc01 = {0.f, 0.f}, acc23 = {0.f, 0.f};
  const v2f vzero = {0.f, 0.f};
  const int tap0[4] = {0, 1, 4, 5};    // W-index of first tap per pixel

#pragma unroll
  for (int j = 0; j < 7; ++j) {        // 7 groups of 4 output rows
    // ---- issue next group's loads (rows base+4j+5 .. +8), 8 VMEM ----
    float4 nvL[4], nvR[4];
    if (j < 6) {
#pragma unroll
      for (int k = 0; k < 4; ++k) {
        nvL[k] = ldL(base + 4 * j + 5 + k);
        nvR[k] = ldR(base + 4 * j + 5 + k);
      }
    }
    __builtin_amdgcn_sched_barrier(0);  // loads may not sink into compute

    // ---- compute group j: packed FMA on WR[0..5], no DS, no lgkm ----
#pragma unroll
    for (int i = 0; i < 4; ++i) {      // output row base+4j+i
      float (&A)[8] = WR[i];
      float (&B)[8] = WR[i + 1];
      float (&C)[8] = WR[i + 2];
#pragma unroll
      for (int p = 0; p < 4; ++p) {
        const int q = tap0[p];
        v2f t01 = PK2(A[q]) * K01[0];
        t01 = __builtin_elementwise_fma(PK2(A[q + 1]), K01[1], t01);
        t01 = __builtin_elementwise_fma(PK2(A[q + 2]), K01[2], t01);
        t01 = __builtin_elementwise_fma(PK2(B[q]),     K01[3], t01);
        t01 = __builtin_elementwise_fma(PK2(B[q + 1]), K01[4], t01);
        t01 = __builtin_elementwise_fma(PK2(B[q + 2]), K01[5], t01);
        t01 = __builtin_elementwise_fma(PK2(C[q]),     K01[6], t01);
        t01 = __builtin_elementwise_fma(PK2(C[q + 1]), K01[7], t01);
        t01 = __builtin_elementwise_fma(PK2(C[q + 2]), K01[8], t01);

        v2f t23 = PK2(A[q]) * K23[0];
        t23 = __builtin_elementwise_fma(PK2(A[q + 1]), K23[1], t23);
        t23 = __builtin_elementwise_fma(PK2(A[q + 2]), K23[2], t23);
        t23 = __builtin_elementwise_fma(PK2(B[q]),     K23[3], t23);
        t23 = __builtin_elementwise_fma(PK2(B[q + 1]), K23[4], t23);
        t23 = __builtin_elementwise_fma(PK2(B[q + 2]), K23[5], t23);
        t23 = __builtin_elementwise_fma(PK2(C[q]),     K23[6], t23);
        t23 = __builtin_elementwise_fma(PK2(C[q + 1]), K23[7], t23);
        t23 = __builtin_elementwise_fma(PK2(C[q + 2]), K23[8], t23);

        acc01 += __builtin_elementwise_max(t01, vzero);
        acc23 += __builtin_elementwise_max(t23, vzero);
      }
    }
    __builtin_amdgcn_sched_barrier(0);  // compute may not sink below roll

    // ---- roll window; build arrived rows (vmcnt wait lands here) ----
    if (j < 6) {
#pragma unroll
      for (int q = 0; q < 8; ++q) { WR[0][q] = WR[4][q]; WR[1][q] = WR[5][q]; }
#pragma unroll
      for (int k = 0; k < 4; ++k) mkW(nvL[k], nvR[k], WR[2 + k]);
      // bottom strip: row 224 (clamped load at j==5,k==3) must be zero
      if (j == 5 && s == 7) {
#pragma unroll
        for (int q = 0; q < 8; ++q) WR[5][q] = 0.f;
      }
    }
  }

  float acc0 = acc01.x, acc1 = acc01.y, acc2 = acc23.x, acc3 = acc23.y;

  // lanes 56..63 computed lane55-clamped garbage: zero before reduction
  if (lane >= 56) { acc0 = 0.f; acc1 = 0.f; acc2 = 0.f; acc3 = 0.f; }

  // wave-level reduce; one partial per WAVE (no LDS, no barrier)
#pragma unroll
  for (int off = 32; off > 0; off >>= 1) {
    acc0 += __shfl_down(acc0, off);
    acc1 += __shfl_down(acc1, off);
    acc2 += __shfl_down(acc2, off);
    acc3 += __shfl_down(acc3, off);
  }
  if (lane == 0) {
    *reinterpret_cast<float4*>(part + (size_t)W * 4) =
        make_float4(acc0, acc1, acc2, acc3);
  }
}

// ---------------- Kernel 2a: 4-qubit circuit (1 element per lane) ----------------
__device__ __forceinline__ void ry_sc(float (&sr)[16], float (&si)[16],
                                      float s, float c, int M) {
#pragma unroll
  for (int i = 0; i < 16; ++i) {
    if (!(i & M)) {
      const int j = i | M;
      float r0 = sr[i], q0 = si[i], r1 = sr[j], q1 = si[j];
      sr[i] = c * r0 - s * r1;  si[i] = c * q0 - s * q1;
      sr[j] = s * r0 + c * r1;  si[j] = s * q0 + c * q1;
    }
  }
}

__device__ __forceinline__ void rz_sc(float (&sr)[16], float (&si)[16],
                                      float s, float c, int M) {
#pragma unroll
  for (int i = 0; i < 16; ++i) {
    float a = sr[i], q = si[i];
    if (i & M) { sr[i] = a * c - q * s;  si[i] = q * c + a * s; }
    else       { sr[i] = a * c + q * s;  si[i] = q * c - a * s; }
  }
}

__device__ __forceinline__ void cnot_g(float (&sr)[16], float (&si)[16],
                                       int MC, int MT) {
#pragma unroll
  for (int i = 0; i < 16; ++i) {
    if ((i & MC) && !(i & MT)) {
      const int j = i | MT;
      float tr = sr[i]; sr[i] = sr[j]; sr[j] = tr;
      float ti = si[i]; si[i] = si[j]; si[j] = ti;
    }
  }
}

__global__ __launch_bounds__(64) void circuit_k(
    const float* __restrict__ part, const float* __restrict__ params,
    float* __restrict__ ev_out)
{
  const int tid = threadIdx.x;
  const int e = blockIdx.x * 64 + tid;   // batch element

  __shared__ float scs[24], scc[24];     // sin/cos of 0.5*param[i]
  if (tid < 24) {
    float s, c;
    sincosf(0.5f * params[tid], &s, &c);
    scs[tid] = s; scc[tid] = c;
  }
  __syncthreads();

  float4 fs = make_float4(0.f, 0.f, 0.f, 0.f);
#pragma unroll
  for (int s8 = 0; s8 < GROUPS; ++s8) {
    const float4 q = *reinterpret_cast<const float4*>(&part[(e * GROUPS + s8) * 4]);
    fs.x += q.x; fs.y += q.y; fs.z += q.z; fs.w += q.w;
  }
  const float f[4] = { fs.x * (1.0f / NPIX), fs.y * (1.0f / NPIX),
                       fs.z * (1.0f / NPIX), fs.w * (1.0f / NPIX) };

  float sr[16], si[16];
#pragma unroll
  for (int i = 0; i < 16; ++i) { sr[i] = 0.f; si[i] = 0.f; }
  sr[0] = 1.f;

#pragma unroll
  for (int w = 0; w < 4; ++w) {
    float s, c;
    sincosf(0.5f * f[w], &s, &c);
    ry_sc(sr, si, s, c, 8 >> w);
  }

#pragma unroll
  for (int l = 0; l < NL; ++l) {
#pragma unroll
    for (int w = 0; w < 4; ++w) {
      const int idx = l * 8 + w * 2;
      ry_sc(sr, si, scs[idx],     scc[idx],     8 >> w);
      rz_sc(sr, si, scs[idx + 1], scc[idx + 1], 8 >> w);
    }
    cnot_g(sr, si, 8, 4);
    cnot_g(sr, si, 4, 2);
    cnot_g(sr, si, 2, 1);
  }

  float p[16];
#pragma unroll
  for (int i = 0; i < 16; ++i) p[i] = sr[i] * sr[i] + si[i] * si[i];

#pragma unroll
  for (int w = 0; w < 4; ++w) {
    const int m = 8 >> w;
    float ssum = 0.f;
#pragma unroll
    for (int i = 0; i < 16; ++i) ssum += (i & m) ? -p[i] : p[i];
    ev_out[e * 4 + w] = ssum;
  }
}

// ---------------- Kernel 2b: BatchNorm over batch (deterministic) ----------------
__global__ __launch_bounds__(512) void bn_k(
    const float* __restrict__ ev_in, const float* __restrict__ gamma,
    const float* __restrict__ beta, float* __restrict__ out)
{
  const int b = threadIdx.x;   // batch element
  const float4 e4 = *reinterpret_cast<const float4*>(&ev_in[b * 4]);
  float ev[4] = { e4.x, e4.y, e4.z, e4.w };

  float sum[4], sq[4];
#pragma unroll
  for (int w = 0; w < 4; ++w) { sum[w] = ev[w]; sq[w] = ev[w] * ev[w]; }
#pragma unroll
  for (int off = 32; off > 0; off >>= 1) {
#pragma unroll
    for (int w = 0; w < 4; ++w) {
      sum[w] += __shfl_down(sum[w], off);
      sq[w]  += __shfl_down(sq[w],  off);
    }
  }
  __shared__ float psum[8][4], psq[8][4];
  __shared__ float mean_s[4], rstd_s[4];
  const int wave = b >> 6;
  const int lane = b & 63;
  if (lane == 0) {
#pragma unroll
    for (int w = 0; w < 4; ++w) { psum[wave][w] = sum[w]; psq[wave][w] = sq[w]; }
  }
  __syncthreads();
  if (b < 4) {
    float ssum = 0.f, q = 0.f;
#pragma unroll
    for (int wv = 0; wv < 8; ++wv) { ssum += psum[wv][b]; q += psq[wv][b]; }
    const float m = ssum * (1.0f / BATCH);
    const float v = q * (1.0f / BATCH) - m * m;
    mean_s[b] = m;
    rstd_s[b] = rsqrtf(v + EPSV);
  }
  __syncthreads();
#pragma unroll
  for (int w = 0; w < 4; ++w) {
    out[b * 4 + w] = gamma[w] * (ev[w] - mean_s[w]) * rstd_s[w] + beta[w];
  }
}

extern "C" void kernel_launch(void* const* d_in, const int* in_sizes, int n_in,
                              void* d_out, int out_size, void* d_ws, size_t ws_size,
                              hipStream_t stream) {
  const float* x      = (const float*)d_in[0];
  const float* cw     = (const float*)d_in[1];
  const float* params = (const float*)d_in[2];
  const float* gamma  = (const float*)d_in[3];
  const float* beta   = (const float*)d_in[4];
  float* out  = (float*)d_out;
  float* part = (float*)d_ws;                       // 4096 waves * 4 f32 (64 KB)
  float* ev   = (float*)d_ws + BATCH * GROUPS * 4;  // 512 * 4 f32 (8 KB)

  const int B = in_sizes[0] / NPIX;  // 512

  conv_pool_k<<<B * GROUPS / 4, 256, 0, stream>>>(x, cw, part);
  circuit_k<<<BATCH / 64, 64, 0, stream>>>(part, params, ev);
  bn_k<<<1, 512, 0, stream>>>(ev, gamma, beta, out);
}

// Round 22
// 40.152 us; speedup vs baseline: 1.3026x; 1.3026x over previous
//
#include <hip/hip_runtime.h>
#include <math.h>

#define BATCH 512
#define HH 224
#define WW 224
#define NPIX (HH * WW)
#define NL 3
#define EPSV 1e-5f
#define GROUPS 8             // strips per image (one per WAVE), 28 rows each

typedef float v2f __attribute__((ext_vector_type(2)));
#define PK2(s) ((v2f){(s), (s)})

// ---------------- Kernel 1: conv3x3(1->4) + relu + partial sums ----------------
// FINAL (R18 verbatim — best measured, 40.18us total). Persistent per-wave
// pipeline + packed-fp32 math. Channels (0,1)/(2,3) in v2f lanes: 18 pk_fma/px
// (vs 36 scalar FMA). Per wave: 28-row strip, 7 groups of 4 output rows:
//   [issue nv loads] SBAR [packed FMA on E[0..5]] SBAR [roll E + expand nv]
// R21 falsified the DS-stall theory (no-shfl dual-load: VGPR 152, 52us);
// R19/R20 falsified TLP and repack theories. This config is the local optimum.
// Lessons: R2 zero clamped lanes pre-reduce; R5 no min-waves clause; R6/R9
// loads sink unless fenced; R13 per-wave partials; R18 packed issue halving.
__global__ __launch_bounds__(256) void conv_pool_k(
    const float* __restrict__ x, const float* __restrict__ cw,
    float* __restrict__ part)
{
  const int tid = threadIdx.x;
  const int wv = tid >> 6;
  const int lane = tid & 63;
  const int W = blockIdx.x * 4 + wv;   // global wave id
  const int b = W >> 3;                // image
  const int s = W & 7;                 // strip
  const int base = s * 28;             // first output row of strip
  const int colc = (lane < 56 ? lane : 55) * 4;  // clamped col
  const float* __restrict__ img = x + (size_t)b * NPIX;

  // packed weights: lane0=ch0/ch2, lane1=ch1/ch3 (wave-uniform -> SGPR pairs)
  v2f K01[9], K23[9];
#pragma unroll
  for (int k = 0; k < 9; ++k) {
    K01[k] = (v2f){cw[k],      cw[9 + k]};
    K23[k] = (v2f){cw[18 + k], cw[27 + k]};
  }

  auto ldrow = [&](int ar) -> float4 {
    int rc = ar < 0 ? 0 : (ar > HH - 1 ? HH - 1 : ar);
    return *reinterpret_cast<const float4*>(img + (size_t)rc * WW + colc);
  };
  auto expand = [&](const float4& t, float (&R)[6]) {
    float lft = __shfl_up(t.w, 1);
    R[0] = (lane == 0) ? 0.f : lft;     // image left edge
    float rgt = __shfl_down(t.x, 1);
    R[5] = (lane == 55) ? 0.f : rgt;    // image right edge (lane56 dups lane55)
    R[1] = t.x; R[2] = t.y; R[3] = t.z; R[4] = t.w;
  };

  // prologue: load + expand window rows base-1 .. base+4 into E[0..5]
  float E[6][6];
  {
    float4 rv[6];
#pragma unroll
    for (int k = 0; k < 6; ++k) rv[k] = ldrow(base - 1 + k);
    if (s == 0) rv[0] = make_float4(0.f, 0.f, 0.f, 0.f);  // row -1
#pragma unroll
    for (int k = 0; k < 6; ++k) expand(rv[k], E[k]);
  }

  v2f acc01 = {0.f, 0.f}, acc23 = {0.f, 0.f};
  const v2f vzero = {0.f, 0.f};

#pragma unroll
  for (int j = 0; j < 7; ++j) {        // 7 groups of 4 output rows
    // ---- issue next group's loads (rows base+4j+5 .. +8) ----
    float4 nv[4];
    if (j < 6) {
#pragma unroll
      for (int k = 0; k < 4; ++k) nv[k] = ldrow(base + 4 * j + 5 + k);
    }
    __builtin_amdgcn_sched_barrier(0);  // loads may not sink into compute

    // ---- compute group j: packed FMA on E[0..5], no DS ops, no waits ----
#pragma unroll
    for (int i = 0; i < 4; ++i) {      // output row base+4j+i
      float (&A)[6] = E[i];
      float (&B)[6] = E[i + 1];
      float (&C)[6] = E[i + 2];
#pragma unroll
      for (int p = 0; p < 4; ++p) {
        v2f t01 = PK2(A[p]) * K01[0];
        t01 = __builtin_elementwise_fma(PK2(A[p + 1]), K01[1], t01);
        t01 = __builtin_elementwise_fma(PK2(A[p + 2]), K01[2], t01);
        t01 = __builtin_elementwise_fma(PK2(B[p]),     K01[3], t01);
        t01 = __builtin_elementwise_fma(PK2(B[p + 1]), K01[4], t01);
        t01 = __builtin_elementwise_fma(PK2(B[p + 2]), K01[5], t01);
        t01 = __builtin_elementwise_fma(PK2(C[p]),     K01[6], t01);
        t01 = __builtin_elementwise_fma(PK2(C[p + 1]), K01[7], t01);
        t01 = __builtin_elementwise_fma(PK2(C[p + 2]), K01[8], t01);

        v2f t23 = PK2(A[p]) * K23[0];
        t23 = __builtin_elementwise_fma(PK2(A[p + 1]), K23[1], t23);
        t23 = __builtin_elementwise_fma(PK2(A[p + 2]), K23[2], t23);
        t23 = __builtin_elementwise_fma(PK2(B[p]),     K23[3], t23);
        t23 = __builtin_elementwise_fma(PK2(B[p + 1]), K23[4], t23);
        t23 = __builtin_elementwise_fma(PK2(B[p + 2]), K23[5], t23);
        t23 = __builtin_elementwise_fma(PK2(C[p]),     K23[6], t23);
        t23 = __builtin_elementwise_fma(PK2(C[p + 1]), K23[7], t23);
        t23 = __builtin_elementwise_fma(PK2(C[p + 2]), K23[8], t23);

        acc01 += __builtin_elementwise_max(t01, vzero);
        acc23 += __builtin_elementwise_max(t23, vzero);
      }
    }
    __builtin_amdgcn_sched_barrier(0);  // compute may not sink below roll

    // ---- roll in E-space; expand arrived nv rows (vmcnt wait lands here) ----
    if (j < 6) {
#pragma unroll
      for (int q = 0; q < 6; ++q) { E[0][q] = E[4][q]; E[1][q] = E[5][q]; }
      if (j == 5 && s == 7) nv[3] = make_float4(0.f, 0.f, 0.f, 0.f);  // row 224
#pragma unroll
      for (int k = 0; k < 4; ++k) expand(nv[k], E[2 + k]);
    }
  }

  float acc0 = acc01.x, acc1 = acc01.y, acc2 = acc23.x, acc3 = acc23.y;

  // lanes 56..63 computed lane55's duplicate columns: zero before reduction
  if (lane >= 56) { acc0 = 0.f; acc1 = 0.f; acc2 = 0.f; acc3 = 0.f; }

  // wave-level reduce; one partial per WAVE (no LDS, no barrier)
#pragma unroll
  for (int off = 32; off > 0; off >>= 1) {
    acc0 += __shfl_down(acc0, off);
    acc1 += __shfl_down(acc1, off);
    acc2 += __shfl_down(acc2, off);
    acc3 += __shfl_down(acc3, off);
  }
  if (lane == 0) {
    *reinterpret_cast<float4*>(part + (size_t)W * 4) =
        make_float4(acc0, acc1, acc2, acc3);
  }
}

// ---------------- Kernel 2a: 4-qubit circuit (1 element per lane) ----------------
__device__ __forceinline__ void ry_sc(float (&sr)[16], float (&si)[16],
                                      float s, float c, int M) {
#pragma unroll
  for (int i = 0; i < 16; ++i) {
    if (!(i & M)) {
      const int j = i | M;
      float r0 = sr[i], q0 = si[i], r1 = sr[j], q1 = si[j];
      sr[i] = c * r0 - s * r1;  si[i] = c * q0 - s * q1;
      sr[j] = s * r0 + c * r1;  si[j] = s * q0 + c * q1;
    }
  }
}

__device__ __forceinline__ void rz_sc(float (&sr)[16], float (&si)[16],
                                      float s, float c, int M) {
#pragma unroll
  for (int i = 0; i < 16; ++i) {
    float a = sr[i], q = si[i];
    if (i & M) { sr[i] = a * c - q * s;  si[i] = q * c + a * s; }
    else       { sr[i] = a * c + q * s;  si[i] = q * c - a * s; }
  }
}

__device__ __forceinline__ void cnot_g(float (&sr)[16], float (&si)[16],
                                       int MC, int MT) {
#pragma unroll
  for (int i = 0; i < 16; ++i) {
    if ((i & MC) && !(i & MT)) {
      const int j = i | MT;
      float tr = sr[i]; sr[i] = sr[j]; sr[j] = tr;
      float ti = si[i]; si[i] = si[j]; si[j] = ti;
    }
  }
}

__global__ __launch_bounds__(64) void circuit_k(
    const float* __restrict__ part, const float* __restrict__ params,
    float* __restrict__ ev_out)
{
  const int tid = threadIdx.x;
  const int e = blockIdx.x * 64 + tid;   // batch element

  __shared__ float scs[24], scc[24];     // sin/cos of 0.5*param[i]
  if (tid < 24) {
    float s, c;
    sincosf(0.5f * params[tid], &s, &c);
    scs[tid] = s; scc[tid] = c;
  }
  __syncthreads();

  float4 fs = make_float4(0.f, 0.f, 0.f, 0.f);
#pragma unroll
  for (int s8 = 0; s8 < GROUPS; ++s8) {
    const float4 q = *reinterpret_cast<const float4*>(&part[(e * GROUPS + s8) * 4]);
    fs.x += q.x; fs.y += q.y; fs.z += q.z; fs.w += q.w;
  }
  const float f[4] = { fs.x * (1.0f / NPIX), fs.y * (1.0f / NPIX),
                       fs.z * (1.0f / NPIX), fs.w * (1.0f / NPIX) };

  float sr[16], si[16];
#pragma unroll
  for (int i = 0; i < 16; ++i) { sr[i] = 0.f; si[i] = 0.f; }
  sr[0] = 1.f;

#pragma unroll
  for (int w = 0; w < 4; ++w) {
    float s, c;
    sincosf(0.5f * f[w], &s, &c);
    ry_sc(sr, si, s, c, 8 >> w);
  }

#pragma unroll
  for (int l = 0; l < NL; ++l) {
#pragma unroll
    for (int w = 0; w < 4; ++w) {
      const int idx = l * 8 + w * 2;
      ry_sc(sr, si, scs[idx],     scc[idx],     8 >> w);
      rz_sc(sr, si, scs[idx + 1], scc[idx + 1], 8 >> w);
    }
    cnot_g(sr, si, 8, 4);
    cnot_g(sr, si, 4, 2);
    cnot_g(sr, si, 2, 1);
  }

  float p[16];
#pragma unroll
  for (int i = 0; i < 16; ++i) p[i] = sr[i] * sr[i] + si[i] * si[i];

#pragma unroll
  for (int w = 0; w < 4; ++w) {
    const int m = 8 >> w;
    float ssum = 0.f;
#pragma unroll
    for (int i = 0; i < 16; ++i) ssum += (i & m) ? -p[i] : p[i];
    ev_out[e * 4 + w] = ssum;
  }
}

// ---------------- Kernel 2b: BatchNorm over batch (deterministic) ----------------
__global__ __launch_bounds__(512) void bn_k(
    const float* __restrict__ ev_in, const float* __restrict__ gamma,
    const float* __restrict__ beta, float* __restrict__ out)
{
  const int b = threadIdx.x;   // batch element
  const float4 e4 = *reinterpret_cast<const float4*>(&ev_in[b * 4]);
  float ev[4] = { e4.x, e4.y, e4.z, e4.w };

  float sum[4], sq[4];
#pragma unroll
  for (int w = 0; w < 4; ++w) { sum[w] = ev[w]; sq[w] = ev[w] * ev[w]; }
#pragma unroll
  for (int off = 32; off > 0; off >>= 1) {
#pragma unroll
    for (int w = 0; w < 4; ++w) {
      sum[w] += __shfl_down(sum[w], off);
      sq[w]  += __shfl_down(sq[w],  off);
    }
  }
  __shared__ float psum[8][4], psq[8][4];
  __shared__ float mean_s[4], rstd_s[4];
  const int wave = b >> 6;
  const int lane = b & 63;
  if (lane == 0) {
#pragma unroll
    for (int w = 0; w < 4; ++w) { psum[wave][w] = sum[w]; psq[wave][w] = sq[w]; }
  }
  __syncthreads();
  if (b < 4) {
    float ssum = 0.f, q = 0.f;
#pragma unroll
    for (int wv = 0; wv < 8; ++wv) { ssum += psum[wv][b]; q += psq[wv][b]; }
    const float m = ssum * (1.0f / BATCH);
    const float v = q * (1.0f / BATCH) - m * m;
    mean_s[b] = m;
    rstd_s[b] = rsqrtf(v + EPSV);
  }
  __syncthreads();
#pragma unroll
  for (int w = 0; w < 4; ++w) {
    out[b * 4 + w] = gamma[w] * (ev[w] - mean_s[w]) * rstd_s[w] + beta[w];
  }
}

extern "C" void kernel_launch(void* const* d_in, const int* in_sizes, int n_in,
                              void* d_out, int out_size, void* d_ws, size_t ws_size,
                              hipStream_t stream) {
  const float* x      = (const float*)d_in[0];
  const float* cw     = (const float*)d_in[1];
  const float* params = (const float*)d_in[2];
  const float* gamma  = (const float*)d_in[3];
  const float* beta   = (const float*)d_in[4];
  float* out  = (float*)d_out;
  float* part = (float*)d_ws;                       // 4096 waves * 4 f32 (64 KB)
  float* ev   = (float*)d_ws + BATCH * GROUPS * 4;  // 512 * 4 f32 (8 KB)

  const int B = in_sizes[0] / NPIX;  // 512

  conv_pool_k<<<B * GROUPS / 4, 256, 0, stream>>>(x, cw, part);
  circuit_k<<<BATCH / 64, 64, 0, stream>>>(part, params, ev);
  bn_k<<<1, 512, 0, stream>>>(ev, gamma, beta, out);
}

// Round 23
// 40.144 us; speedup vs baseline: 1.3029x; 1.0002x over previous
//
#include <hip/hip_runtime.h>
#include <math.h>

#define BATCH 512
#define HH 224
#define WW 224
#define NPIX (HH * WW)
#define NL 3
#define EPSV 1e-5f
#define GROUPS 8             // strips per image (one per WAVE), 28 rows each

typedef float v2f __attribute__((ext_vector_type(2)));
#define PK2(s) ((v2f){(s), (s)})

// ---------------- Kernel 1: conv3x3(1->4) + relu + partial sums ----------------
// R18 structure WITHOUT the sched_barrier(0) fences (final single-variable A/B).
// Theory: post-packing, the fenced [loads][FMA][roll+shfl] phases over-serialize
// — the roll phase (8 ds_bpermute + ~40 movs/group) runs with VALU idle and the
// walls forbid overlapping it with the next group's (now 2x smaller) FMA block.
// Without fences the compiler may software-pipeline roll∥FMA. Risk: loads sink
// (R6 behavior) -> regress to ~47; then R18 (fenced) is the final answer.
__global__ __launch_bounds__(256) void conv_pool_k(
    const float* __restrict__ x, const float* __restrict__ cw,
    float* __restrict__ part)
{
  const int tid = threadIdx.x;
  const int wv = tid >> 6;
  const int lane = tid & 63;
  const int W = blockIdx.x * 4 + wv;   // global wave id
  const int b = W >> 3;                // image
  const int s = W & 7;                 // strip
  const int base = s * 28;             // first output row of strip
  const int colc = (lane < 56 ? lane : 55) * 4;  // clamped col
  const float* __restrict__ img = x + (size_t)b * NPIX;

  // packed weights: ch(0,1) and ch(2,3) pairs (wave-uniform)
  v2f K01[9], K23[9];
#pragma unroll
  for (int k = 0; k < 9; ++k) {
    K01[k] = (v2f){cw[k],      cw[9 + k]};
    K23[k] = (v2f){cw[18 + k], cw[27 + k]};
  }

  auto ldrow = [&](int ar) -> float4 {
    int rc = ar < 0 ? 0 : (ar > HH - 1 ? HH - 1 : ar);
    return *reinterpret_cast<const float4*>(img + (size_t)rc * WW + colc);
  };
  auto expand = [&](const float4& t, float (&R)[6]) {
    float lft = __shfl_up(t.w, 1);
    R[0] = (lane == 0) ? 0.f : lft;     // image left edge
    float rgt = __shfl_down(t.x, 1);
    R[5] = (lane == 55) ? 0.f : rgt;    // image right edge (lane56 dups lane55)
    R[1] = t.x; R[2] = t.y; R[3] = t.z; R[4] = t.w;
  };

  // prologue: load + expand window rows base-1 .. base+4 into E[0..5]
  float E[6][6];
  {
    float4 rv[6];
#pragma unroll
    for (int k = 0; k < 6; ++k) rv[k] = ldrow(base - 1 + k);
    if (s == 0) rv[0] = make_float4(0.f, 0.f, 0.f, 0.f);  // row -1
#pragma unroll
    for (int k = 0; k < 6; ++k) expand(rv[k], E[k]);
  }

  v2f acc01 = {0.f, 0.f}, acc23 = {0.f, 0.f};
  const v2f vzero = {0.f, 0.f};

#pragma unroll
  for (int j = 0; j < 7; ++j) {        // 7 groups of 4 output rows
    // ---- issue next group's loads (rows base+4j+5 .. +8) ----
    float4 nv[4];
    if (j < 6) {
#pragma unroll
      for (int k = 0; k < 4; ++k) nv[k] = ldrow(base + 4 * j + 5 + k);
    }
    // (no fence — let the scheduler interleave loads/FMA/roll)

    // ---- compute group j: packed FMA on E[0..5] ----
#pragma unroll
    for (int i = 0; i < 4; ++i) {      // output row base+4j+i
      float (&A)[6] = E[i];
      float (&B)[6] = E[i + 1];
      float (&C)[6] = E[i + 2];
#pragma unroll
      for (int p = 0; p < 4; ++p) {
        v2f t01 = PK2(A[p]) * K01[0];
        t01 = __builtin_elementwise_fma(PK2(A[p + 1]), K01[1], t01);
        t01 = __builtin_elementwise_fma(PK2(A[p + 2]), K01[2], t01);
        t01 = __builtin_elementwise_fma(PK2(B[p]),     K01[3], t01);
        t01 = __builtin_elementwise_fma(PK2(B[p + 1]), K01[4], t01);
        t01 = __builtin_elementwise_fma(PK2(B[p + 2]), K01[5], t01);
        t01 = __builtin_elementwise_fma(PK2(C[p]),     K01[6], t01);
        t01 = __builtin_elementwise_fma(PK2(C[p + 1]), K01[7], t01);
        t01 = __builtin_elementwise_fma(PK2(C[p + 2]), K01[8], t01);

        v2f t23 = PK2(A[p]) * K23[0];
        t23 = __builtin_elementwise_fma(PK2(A[p + 1]), K23[1], t23);
        t23 = __builtin_elementwise_fma(PK2(A[p + 2]), K23[2], t23);
        t23 = __builtin_elementwise_fma(PK2(B[p]),     K23[3], t23);
        t23 = __builtin_elementwise_fma(PK2(B[p + 1]), K23[4], t23);
        t23 = __builtin_elementwise_fma(PK2(B[p + 2]), K23[5], t23);
        t23 = __builtin_elementwise_fma(PK2(C[p]),     K23[6], t23);
        t23 = __builtin_elementwise_fma(PK2(C[p + 1]), K23[7], t23);
        t23 = __builtin_elementwise_fma(PK2(C[p + 2]), K23[8], t23);

        acc01 += __builtin_elementwise_max(t01, vzero);
        acc23 += __builtin_elementwise_max(t23, vzero);
      }
    }

    // ---- roll in E-space; expand arrived nv rows ----
    if (j < 6) {
#pragma unroll
      for (int q = 0; q < 6; ++q) { E[0][q] = E[4][q]; E[1][q] = E[5][q]; }
      if (j == 5 && s == 7) nv[3] = make_float4(0.f, 0.f, 0.f, 0.f);  // row 224
#pragma unroll
      for (int k = 0; k < 4; ++k) expand(nv[k], E[2 + k]);
    }
  }

  float acc0 = acc01.x, acc1 = acc01.y, acc2 = acc23.x, acc3 = acc23.y;

  // lanes 56..63 computed lane55's duplicate columns: zero before reduction
  if (lane >= 56) { acc0 = 0.f; acc1 = 0.f; acc2 = 0.f; acc3 = 0.f; }

  // wave-level reduce; one partial per WAVE (no LDS, no barrier)
#pragma unroll
  for (int off = 32; off > 0; off >>= 1) {
    acc0 += __shfl_down(acc0, off);
    acc1 += __shfl_down(acc1, off);
    acc2 += __shfl_down(acc2, off);
    acc3 += __shfl_down(acc3, off);
  }
  if (lane == 0) {
    *reinterpret_cast<float4*>(part + (size_t)W * 4) =
        make_float4(acc0, acc1, acc2, acc3);
  }
}

// ---------------- Kernel 2a: 4-qubit circuit (1 element per lane) ----------------
__device__ __forceinline__ void ry_sc(float (&sr)[16], float (&si)[16],
                                      float s, float c, int M) {
#pragma unroll
  for (int i = 0; i < 16; ++i) {
    if (!(i & M)) {
      const int j = i | M;
      float r0 = sr[i], q0 = si[i], r1 = sr[j], q1 = si[j];
      sr[i] = c * r0 - s * r1;  si[i] = c * q0 - s * q1;
      sr[j] = s * r0 + c * r1;  si[j] = s * q0 + c * q1;
    }
  }
}

__device__ __forceinline__ void rz_sc(float (&sr)[16], float (&si)[16],
                                      float s, float c, int M) {
#pragma unroll
  for (int i = 0; i < 16; ++i) {
    float a = sr[i], q = si[i];
    if (i & M) { sr[i] = a * c - q * s;  si[i] = q * c + a * s; }
    else       { sr[i] = a * c + q * s;  si[i] = q * c - a * s; }
  }
}

__device__ __forceinline__ void cnot_g(float (&sr)[16], float (&si)[16],
                                       int MC, int MT) {
#pragma unroll
  for (int i = 0; i < 16; ++i) {
    if ((i & MC) && !(i & MT)) {
      const int j = i | MT;
      float tr = sr[i]; sr[i] = sr[j]; sr[j] = tr;
      float ti = si[i]; si[i] = si[j]; si[j] = ti;
    }
  }
}

__global__ __launch_bounds__(64) void circuit_k(
    const float* __restrict__ part, const float* __restrict__ params,
    float* __restrict__ ev_out)
{
  const int tid = threadIdx.x;
  const int e = blockIdx.x * 64 + tid;   // batch element

  __shared__ float scs[24], scc[24];     // sin/cos of 0.5*param[i]
  if (tid < 24) {
    float s, c;
    sincosf(0.5f * params[tid], &s, &c);
    scs[tid] = s; scc[tid] = c;
  }
  __syncthreads();

  float4 fs = make_float4(0.f, 0.f, 0.f, 0.f);
#pragma unroll
  for (int s8 = 0; s8 < GROUPS; ++s8) {
    const float4 q = *reinterpret_cast<const float4*>(&part[(e * GROUPS + s8) * 4]);
    fs.x += q.x; fs.y += q.y; fs.z += q.z; fs.w += q.w;
  }
  const float f[4] = { fs.x * (1.0f / NPIX), fs.y * (1.0f / NPIX),
                       fs.z * (1.0f / NPIX), fs.w * (1.0f / NPIX) };

  float sr[16], si[16];
#pragma unroll
  for (int i = 0; i < 16; ++i) { sr[i] = 0.f; si[i] = 0.f; }
  sr[0] = 1.f;

#pragma unroll
  for (int w = 0; w < 4; ++w) {
    float s, c;
    sincosf(0.5f * f[w], &s, &c);
    ry_sc(sr, si, s, c, 8 >> w);
  }

#pragma unroll
  for (int l = 0; l < NL; ++l) {
#pragma unroll
    for (int w = 0; w < 4; ++w) {
      const int idx = l * 8 + w * 2;
      ry_sc(sr, si, scs[idx],     scc[idx],     8 >> w);
      rz_sc(sr, si, scs[idx + 1], scc[idx + 1], 8 >> w);
    }
    cnot_g(sr, si, 8, 4);
    cnot_g(sr, si, 4, 2);
    cnot_g(sr, si, 2, 1);
  }

  float p[16];
#pragma unroll
  for (int i = 0; i < 16; ++i) p[i] = sr[i] * sr[i] + si[i] * si[i];

#pragma unroll
  for (int w = 0; w < 4; ++w) {
    const int m = 8 >> w;
    float ssum = 0.f;
#pragma unroll
    for (int i = 0; i < 16; ++i) ssum += (i & m) ? -p[i] : p[i];
    ev_out[e * 4 + w] = ssum;
  }
}

// ---------------- Kernel 2b: BatchNorm over batch (deterministic) ----------------
__global__ __launch_bounds__(512) void bn_k(
    const float* __restrict__ ev_in, const float* __restrict__ gamma,
    const float* __restrict__ beta, float* __restrict__ out)
{
  const int b = threadIdx.x;   // batch element
  const float4 e4 = *reinterpret_cast<const float4*>(&ev_in[b * 4]);
  float ev[4] = { e4.x, e4.y, e4.z, e4.w };

  float sum[4], sq[4];
#pragma unroll
  for (int w = 0; w < 4; ++w) { sum[w] = ev[w]; sq[w] = ev[w] * ev[w]; }
#pragma unroll
  for (int off = 32; off > 0; off >>= 1) {
#pragma unroll
    for (int w = 0; w < 4; ++w) {
      sum[w] += __shfl_down(sum[w], off);
      sq[w]  += __shfl_down(sq[w],  off);
    }
  }
  __shared__ float psum[8][4], psq[8][4];
  __shared__ float mean_s[4], rstd_s[4];
  const int wave = b >> 6;
  const int lane = b & 63;
  if (lane == 0) {
#pragma unroll
    for (int w = 0; w < 4; ++w) { psum[wave][w] = sum[w]; psq[wave][w] = sq[w]; }
  }
  __syncthreads();
  if (b < 4) {
    float ssum = 0.f, q = 0.f;
#pragma unroll
    for (int wv = 0; wv < 8; ++wv) { ssum += psum[wv][b]; q += psq[wv][b]; }
    const float m = ssum * (1.0f / BATCH);
    const float v = q * (1.0f / BATCH) - m * m;
    mean_s[b] = m;
    rstd_s[b] = rsqrtf(v + EPSV);
  }
  __syncthreads();
#pragma unroll
  for (int w = 0; w < 4; ++w) {
    out[b * 4 + w] = gamma[w] * (ev[w] - mean_s[w]) * rstd_s[w] + beta[w];
  }
}

extern "C" void kernel_launch(void* const* d_in, const int* in_sizes, int n_in,
                              void* d_out, int out_size, void* d_ws, size_t ws_size,
                              hipStream_t stream) {
  const float* x      = (const float*)d_in[0];
  const float* cw     = (const float*)d_in[1];
  const float* params = (const float*)d_in[2];
  const float* gamma  = (const float*)d_in[3];
  const float* beta   = (const float*)d_in[4];
  float* out  = (float*)d_out;
  float* part = (float*)d_ws;                       // 4096 waves * 4 f32 (64 KB)
  float* ev   = (float*)d_ws + BATCH * GROUPS * 4;  // 512 * 4 f32 (8 KB)

  const int B = in_sizes[0] / NPIX;  // 512

  conv_pool_k<<<B * GROUPS / 4, 256, 0, stream>>>(x, cw, part);
  circuit_k<<<BATCH / 64, 64, 0, stream>>>(part, params, ev);
  bn_k<<<1, 512, 0, stream>>>(ev, gamma, beta, out);
}